// Round 5
// baseline (2624.519 us; speedup 1.0000x reference)
//
#include <hip/hip_runtime.h>
#include <math.h>

// ---------------- problem constants ----------------
// B=64, P=196, H=E=A=512, V=10000, T=49, gates=2048, Kx=1536

// ---------------- ws layout (element offsets) ----------------
#define WS_SORT   0             // int[64]
#define WS_DL     64            // int[64]
#define WS_NB     128           // int[64]: nb[0..48], [49]=R
#define WS_ROWOFF 192           // int[64] (50 used)
#define WS_CAPS   256           // int[64*50]
#define WS_RMAP   3456          // int[3136]: t*64+b per compact row
#define WS_H      6592          // float[64*512]
#define WS_C      39360         // float[64*512]
#define WS_ATT2   72128         // float[64*512] (includes b_dec)
#define WS_E      104896        // float[64*200] exp(e) values
#define WS_Z      117696        // float[4][64] expsum partials
#define WS_CTXP   117952        // float[4][64][512] unnormalized ctx partials
#define WS_PG     249024        // float[16][64][2048] gates k-split partials
#define WS_HALL   2346176       // float[3136*512] compact h_new rows
#define WS_ENC    3951808       // float[12544*512] enc_att
// end = 10,374,336 floats = 41.5 MB (proven size)

// ---------------- out layout (floats) ----------------
#define OUT_SCORES 0            // (64,49,10000)
#define OUT_CAPS   31360000     // (64,50)
#define OUT_DL     31363200     // (64,)
#define OUT_W      31363264     // (64,49,196)
#define OUT_SORT   31977920     // (64,)

#define LSW 196                 // swizzled 128-tile row stride (chunks at stride 12)

__device__ __forceinline__ float sigm(float x) { return 1.f / (1.f + expf(-x)); }

__device__ __forceinline__ float4 f4add(float4 a, float4 b) {
  return make_float4(a.x + b.x, a.y + b.y, a.z + b.z, a.w + b.w);
}

// chunk swizzle for 128-tiles: logical col m -> chunk (m>>3) at stride 12
__device__ __forceinline__ int swz128(int m) { return (m >> 3) * 12 + (m & 7); }

// ---------------- 128-tile helpers: 256 threads, KC=16, 8x8 micro, swizzled LDS ----------------
__device__ __forceinline__ void stage128_strided(const float* __restrict__ src, int row0, int ld, int k0,
                                                 float* __restrict__ dst, int tid, int nrows_valid) {
#pragma unroll
  for (int i = 0; i < 2; ++i) {
    int lin = tid + 256 * i;          // 0..511
    int m = lin >> 2, kf = lin & 3;   // m 0..127, kf 0..3
    float4 v = make_float4(0.f, 0.f, 0.f, 0.f);
    if (m < nrows_valid) v = *(const float4*)(src + (long)(row0 + m) * ld + k0 + kf * 4);
    int mc = swz128(m);
    dst[(kf * 4 + 0) * LSW + mc] = v.x;
    dst[(kf * 4 + 1) * LSW + mc] = v.y;
    dst[(kf * 4 + 2) * LSW + mc] = v.z;
    dst[(kf * 4 + 3) * LSW + mc] = v.w;
  }
}

__device__ __forceinline__ void stage128_gather(const float* __restrict__ src, const int* __restrict__ bases,
                                                int k0, float* __restrict__ dst, int tid) {
#pragma unroll
  for (int i = 0; i < 2; ++i) {
    int lin = tid + 256 * i;
    int m = lin >> 2, kf = lin & 3;
    float4 v = *(const float4*)(src + bases[m] + k0 + kf * 4);
    int mc = swz128(m);
    dst[(kf * 4 + 0) * LSW + mc] = v.x;
    dst[(kf * 4 + 1) * LSW + mc] = v.y;
    dst[(kf * 4 + 2) * LSW + mc] = v.z;
    dst[(kf * 4 + 3) * LSW + mc] = v.w;
  }
}

__device__ __forceinline__ void gemm_acc128(const float* __restrict__ As, const float* __restrict__ Bs,
                                            float acc[8][8], int tx, int ty) {
#pragma unroll
  for (int kk = 0; kk < 16; ++kk) {
    const float4* ar = (const float4*)(As + kk * LSW + tx * 12);
    const float4* br = (const float4*)(Bs + kk * LSW + ty * 12);
    float4 a0 = ar[0], a1 = ar[1];
    float4 b0 = br[0], b1 = br[1];
    float av[8] = {a0.x, a0.y, a0.z, a0.w, a1.x, a1.y, a1.z, a1.w};
    float bv[8] = {b0.x, b0.y, b0.z, b0.w, b1.x, b1.y, b1.z, b1.w};
#pragma unroll
    for (int i = 0; i < 8; ++i)
#pragma unroll
      for (int j = 0; j < 8; ++j)
        acc[i][j] = fmaf(av[i], bv[j], acc[i][j]);
  }
}

// ---------------- setup ----------------
__global__ __launch_bounds__(64) void setup_kernel(const int* __restrict__ caps, const int* __restrict__ caplens,
                                                   float* __restrict__ ws, float* __restrict__ out) {
  __shared__ int cl_s[64], so_s[64], dl_s[64], nb_s[49], ro_s[50];
  int i = threadIdx.x;
  cl_s[i] = caplens[i];
  __syncthreads();
  int cli = cl_s[i];
  int r = 0;
  for (int j = 0; j < 64; ++j) {
    int clj = cl_s[j];
    r += (clj > cli) || (clj == cli && j < i);   // stable descending
  }
  so_s[r] = i;
  dl_s[r] = cli - 1;
  __syncthreads();
  int* iws = (int*)ws;
  iws[WS_SORT + i] = so_s[i];
  iws[WS_DL + i] = dl_s[i];
  out[OUT_SORT + i] = (float)so_s[i];
  out[OUT_DL + i] = (float)dl_s[i];
  if (i < 49) {
    int n = 0;
    for (int b = 0; b < 64; ++b) n += (dl_s[b] > i);
    iws[WS_NB + i] = n;
    nb_s[i] = n;
  }
  __syncthreads();
  if (i == 0) {
    int acc = 0;
    for (int t = 0; t < 49; ++t) { ro_s[t] = acc; acc += nb_s[t]; }
    ro_s[49] = acc;
    iws[WS_NB + 49] = acc;
  }
  __syncthreads();
  if (i < 50) iws[WS_ROWOFF + i] = ro_s[i];
  int R = ro_s[49];
  for (int rr = i; rr < 3136; rr += 64) {
    int val = 0;
    if (rr < R) {
      int t = 0;
      while (t < 48 && ro_s[t + 1] <= rr) ++t;
      val = t * 64 + (rr - ro_s[t]);
    }
    iws[WS_RMAP + rr] = val;
  }
  for (int j = i; j < 3200; j += 64) {
    int k = j / 50, jj = j - k * 50;
    int cv = caps[so_s[k] * 50 + jj];
    iws[WS_CAPS + j] = cv;
    out[OUT_CAPS + j] = (float)cv;
  }
}

// ---------------- zero scores+weights+h/c, att2 = b_dec ----------------
__global__ void zero_init_kernel(float* __restrict__ out, float* __restrict__ ws, const float* __restrict__ b_dec) {
  const float4 z = make_float4(0.f, 0.f, 0.f, 0.f);
  float4* out4 = (float4*)out;
  float4* ws4 = (float4*)ws;
  const float4* bd4 = (const float4*)b_dec;
  for (long idx = (long)blockIdx.x * 256 + threadIdx.x; idx < 8018240L; idx += (long)gridDim.x * 256) {
    if (idx < 7840000L) {
      out4[idx] = z;                                   // scores
    } else if (idx < 7993664L) {
      out4[7840816L + (idx - 7840000L)] = z;           // weights
    } else if (idx < 8010048L) {
      ws4[1648L + (idx - 7993664L)] = z;               // h, c
    } else {
      long j = idx - 8010048L;
      ws4[18032L + j] = bd4[j & 127];                  // att2 = b_dec
    }
  }
}

// ---------------- enc_att = feats_sorted @ W_enc^T + b_enc (128-tile, swizzled LDS) ----------------
__global__ __launch_bounds__(256) void encatt_kernel(const float* __restrict__ image, const float* __restrict__ W_enc,
                                                     const float* __restrict__ b_enc, float* __restrict__ ws) {
  __shared__ __align__(16) float As[16 * LSW];
  __shared__ __align__(16) float Bs[16 * LSW];
  __shared__ int rb[128];
  int tid = threadIdx.x;
  const int* iws = (const int*)ws;
  int mt = blockIdx.x, nt = blockIdx.y;
  if (tid < 128) {
    int r = mt * 128 + tid;
    int b = r / 196;
    int p = r - b * 196;
    rb[tid] = iws[WS_SORT + b] * 100352 + p * 512;
  }
  float acc[8][8] = {};
  for (int ch = 0; ch < 32; ++ch) {
    __syncthreads();
    stage128_gather(image, rb, ch * 16, As, tid);
    stage128_strided(W_enc, nt * 128, 512, ch * 16, Bs, tid, 128);
    __syncthreads();
    gemm_acc128(As, Bs, acc, tid & 15, tid >> 4);
  }
  int tx = tid & 15, ty = tid >> 4;
  int r0 = mt * 128 + tx * 8;
  int n0 = nt * 128 + ty * 8;
#pragma unroll
  for (int i = 0; i < 8; ++i) {
    float* cp = ws + WS_ENC + (long)(r0 + i) * 512 + n0;
    *(float4*)(cp)     = make_float4(acc[i][0] + b_enc[n0],     acc[i][1] + b_enc[n0 + 1],
                                     acc[i][2] + b_enc[n0 + 2], acc[i][3] + b_enc[n0 + 3]);
    *(float4*)(cp + 4) = make_float4(acc[i][4] + b_enc[n0 + 4], acc[i][5] + b_enc[n0 + 5],
                                     acc[i][6] + b_enc[n0 + 6], acc[i][7] + b_enc[n0 + 7]);
  }
}

// ---------------- E: e = relu(enc+att2)@W_full, exp, Z partial, ctx partial (vectorized) ----------------
// grid (64, 4) x 512 threads; att2/W_full in registers, float4 loads throughout
__global__ __launch_bounds__(512) void ectx_kernel(float* __restrict__ ws, const float* __restrict__ image,
                                                   const float* __restrict__ W_full, const float* __restrict__ b_full,
                                                   int t) {
  const int* iws = (const int*)ws;
  int b = blockIdx.x;
  if (b >= iws[WS_NB + t]) return;
  int pg = blockIdx.y;
  __shared__ float e_s[64];
  __shared__ __align__(16) float ctxp_s[2048];
  int tid = threadIdx.x;
  int w = tid >> 6, lane = tid & 63;

  // per-lane register slices: a-set = {lane*4..+3} u {256+lane*4..+3}
  float4 at0 = *(const float4*)(ws + WS_ATT2 + b * 512 + lane * 4);
  float4 at1 = *(const float4*)(ws + WS_ATT2 + b * 512 + 256 + lane * 4);
  float4 wf0 = *(const float4*)(W_full + lane * 4);
  float4 wf1 = *(const float4*)(W_full + 256 + lane * 4);
  float bf0 = b_full[0];

  // e-part: wave w handles p = pg*49 + {w, w+8, ...}
  for (int idx = w; idx < 49; idx += 8) {
    const float* er = ws + WS_ENC + (long)(b * 196 + pg * 49 + idx) * 512;
    float4 e0 = *(const float4*)(er + lane * 4);
    float4 e1 = *(const float4*)(er + 256 + lane * 4);
    float acc = fmaxf(e0.x + at0.x, 0.f) * wf0.x + fmaxf(e0.y + at0.y, 0.f) * wf0.y +
                fmaxf(e0.z + at0.z, 0.f) * wf0.z + fmaxf(e0.w + at0.w, 0.f) * wf0.w +
                fmaxf(e1.x + at1.x, 0.f) * wf1.x + fmaxf(e1.y + at1.y, 0.f) * wf1.y +
                fmaxf(e1.z + at1.z, 0.f) * wf1.z + fmaxf(e1.w + at1.w, 0.f) * wf1.w;
#pragma unroll
    for (int off = 32; off; off >>= 1) acc += __shfl_down(acc, off);
    if (lane == 0) e_s[idx] = expf(acc + bf0);   // |e| small, no max-sub
  }
  __syncthreads();
  if (tid < 49) ws[WS_E + b * 200 + pg * 49 + tid] = e_s[tid];
  if (tid < 64) {   // wave 0: Z partial
    float zv = (tid < 49) ? e_s[tid] : 0.f;
#pragma unroll
    for (int off = 32; off; off >>= 1) zv += __shfl_down(zv, off);
    if (tid == 0) ws[WS_Z + pg * 64 + b] = zv;
  }
  // ctx: row-group rg handles p = {rg, rg+4, ...}, 128 lanes x float4 = 512 dims
  long sb = (long)iws[WS_SORT + b] * 100352;
  int rg = tid >> 7, l1 = tid & 127;
  float4 a = make_float4(0.f, 0.f, 0.f, 0.f);
  for (int idx = rg; idx < 49; idx += 4) {
    float al = e_s[idx];
    float4 v = *(const float4*)(image + sb + (long)(pg * 49 + idx) * 512 + l1 * 4);
    a.x = fmaf(al, v.x, a.x); a.y = fmaf(al, v.y, a.y);
    a.z = fmaf(al, v.z, a.z); a.w = fmaf(al, v.w, a.w);
  }
  *(float4*)(ctxp_s + rg * 512 + l1 * 4) = a;
  __syncthreads();
  if (tid < 128) {
    float4 v0 = *(const float4*)(ctxp_s + tid * 4);
    float4 v1 = *(const float4*)(ctxp_s + 512 + tid * 4);
    float4 v2 = *(const float4*)(ctxp_s + 1024 + tid * 4);
    float4 v3 = *(const float4*)(ctxp_s + 1536 + tid * 4);
    *(float4*)(ws + WS_CTXP + pg * 32768 + b * 512 + tid * 4) =
        make_float4(v0.x + v1.x + v2.x + v3.x, v0.y + v1.y + v2.y + v3.y,
                    v0.z + v1.z + v2.z + v3.z, v0.w + v1.w + v2.w + v3.w);
  }
}

// ---------------- G: gates partial GEMM, tile 64m x 128n x 96k, 256 thr, acc[8][4] ----------------
// grid (16 nt, 16 ks); wave w owns n-range [w*32, w*32+32); 1.5 B-LDS/FMA, FMA-bound
__global__ __launch_bounds__(256) void gates_kernel(float* __restrict__ ws, const float* __restrict__ emb,
                                                    const float* __restrict__ W_ih, const float* __restrict__ W_hh,
                                                    int t) {
  __shared__ __align__(16) float As[96 * 68];    // [k][m], stride 68
  __shared__ __align__(16) float Bs[96 * 132];   // [k][n], stride 132
  __shared__ int rbe[64];
  __shared__ float rcpz_s[64];
  int tid = threadIdx.x;
  int nt = blockIdx.x;   // 0..15
  int ks = blockIdx.y;   // 0..15
  const int* iws = (const int*)ws;
  if (tid < 64) {
    rbe[tid] = iws[WS_CAPS + tid * 50 + t] * 512;
    float zz = ws[WS_Z + tid] + ws[WS_Z + 64 + tid] + ws[WS_Z + 128 + tid] + ws[WS_Z + 192 + tid];
    rcpz_s[tid] = 1.f / zz;
  }
  __syncthreads();
  int k0 = ks * 96;
  // stage A: 64 rows x 24 float4-chunks (k-boundaries 512/1024 are float4-aligned)
#pragma unroll
  for (int i = 0; i < 6; ++i) {
    int c = tid + 256 * i;
    int m = c / 24, kf = c - m * 24;
    int k = k0 + kf * 4;
    float4 v;
    if (k < 512) {
      v = *(const float4*)(emb + (long)rbe[m] + k);
    } else if (k < 1024) {
      const float* base = ws + WS_CTXP + m * 512 + (k - 512);
      float4 v0 = *(const float4*)(base);
      float4 v1 = *(const float4*)(base + 32768);
      float4 v2 = *(const float4*)(base + 65536);
      float4 v3 = *(const float4*)(base + 98304);
      float rz = rcpz_s[m];
      v = make_float4((v0.x + v1.x + v2.x + v3.x) * rz, (v0.y + v1.y + v2.y + v3.y) * rz,
                      (v0.z + v1.z + v2.z + v3.z) * rz, (v0.w + v1.w + v2.w + v3.w) * rz);
    } else {
      v = *(const float4*)(ws + WS_H + m * 512 + (k - 1024));
    }
    float* da = As + (kf * 4) * 68 + m;
    da[0] = v.x; da[68] = v.y; da[136] = v.z; da[204] = v.w;
  }
  // stage B: 128 rows x 24 float4-chunks (each W element read once per iteration)
#pragma unroll
  for (int i = 0; i < 12; ++i) {
    int c = tid + 256 * i;
    int m = c / 24, kf = c - m * 24;
    int k = k0 + kf * 4;
    int row = nt * 128 + m;
    const float* srcB = (k < 1024) ? (W_ih + (long)row * 1024 + k)
                                   : (W_hh + (long)row * 512 + (k - 1024));
    float4 v = *(const float4*)srcB;
    float* db = Bs + (kf * 4) * 132 + m;
    db[0] = v.x; db[132] = v.y; db[264] = v.z; db[396] = v.w;
  }
  __syncthreads();
  int w = tid >> 6, lane = tid & 63;
  int tx = lane & 7, ty = lane >> 3;
  float acc[8][4] = {};
#pragma unroll 4
  for (int kk = 0; kk < 96; ++kk) {
    const float4* ar = (const float4*)(As + kk * 68 + tx * 8);
    float4 a0 = ar[0], a1 = ar[1];
    float4 bv = *(const float4*)(Bs + kk * 132 + w * 32 + ty * 4);
    float av[8] = {a0.x, a0.y, a0.z, a0.w, a1.x, a1.y, a1.z, a1.w};
#pragma unroll
    for (int i = 0; i < 8; ++i) {
      acc[i][0] = fmaf(av[i], bv.x, acc[i][0]);
      acc[i][1] = fmaf(av[i], bv.y, acc[i][1]);
      acc[i][2] = fmaf(av[i], bv.z, acc[i][2]);
      acc[i][3] = fmaf(av[i], bv.w, acc[i][3]);
    }
  }
  float* pg = ws + WS_PG + ks * 131072;
  int j0 = nt * 128 + w * 32 + ty * 4;
#pragma unroll
  for (int i = 0; i < 8; ++i) {
    *(float4*)(pg + (tx * 8 + i) * 2048 + j0) = make_float4(acc[i][0], acc[i][1], acc[i][2], acc[i][3]);
  }
}

// ---------------- S: reduce gates (f4), LSTM cell, h/weights out, att2(t+1); early-exit dead b ----------------
__global__ __launch_bounds__(512) void lstm_att2_kernel(float* __restrict__ ws, const float* __restrict__ b_ih,
                                                        const float* __restrict__ b_hh, const float* __restrict__ W_dec,
                                                        const float* __restrict__ b_dec, float* __restrict__ out, int t) {
  const int* iws = (const int*)ws;
  int b = blockIdx.x;
  if (b >= iws[WS_NB + t]) return;   // nb non-increasing: att2/h/weights for dead b never consumed
  int as = blockIdx.y;               // a-split 0..3
  int hh = threadIdx.x;
  __shared__ __align__(16) float g[2048];
  __shared__ float h_s[512], red[512];
  // float4 partial reduce: thread owns gates [4*tid, 4*tid+4)
  const float4* bi4 = (const float4*)b_ih;
  const float4* bh4 = (const float4*)b_hh;
  float4 A = f4add(bi4[hh], bh4[hh]);
  const float* pgb = ws + WS_PG + b * 2048;
#pragma unroll
  for (int ks = 0; ks < 16; ++ks) {
    A = f4add(A, *(const float4*)(pgb + (long)ks * 131072 + hh * 4));
  }
  *(float4*)(g + hh * 4) = A;
  __syncthreads();
  float gi = g[hh], gf = g[512 + hh], gg = g[1024 + hh], go = g[1536 + hh];
  float c = ws[WS_C + b * 512 + hh];
  float cn = sigm(gf) * c + sigm(gi) * tanhf(gg);
  float hn = sigm(go) * tanhf(cn);
  h_s[hh] = hn;
  if (as == 0) {
    ws[WS_C + b * 512 + hh] = cn;
    ws[WS_H + b * 512 + hh] = hn;
    ws[WS_HALL + (long)(iws[WS_ROWOFF + t] + b) * 512 + hh] = hn;
  }
  if (hh < 49) {   // weights out for this quarter
    float zz = ws[WS_Z + b] + ws[WS_Z + 64 + b] + ws[WS_Z + 128 + b] + ws[WS_Z + 192 + b];
    int p = as * 49 + hh;
    out[OUT_W + (long)(b * 49 + t) * 196 + p] = ws[WS_E + b * 200 + p] / zz;
  }
  __syncthreads();
  // att2(t+1) for a-range [as*128, as*128+128)
  int a = as * 128 + (hh >> 2);
  int part = hh & 3;
  const float* wd = W_dec + (long)a * 512 + part * 128;
  const float* hp = h_s + part * 128;
  float s = 0.f;
#pragma unroll 8
  for (int j = 0; j < 32; ++j) {
    float4 wv = *(const float4*)(wd + 4 * j);
    s = fmaf(hp[4 * j], wv.x, s);
    s = fmaf(hp[4 * j + 1], wv.y, s);
    s = fmaf(hp[4 * j + 2], wv.z, s);
    s = fmaf(hp[4 * j + 3], wv.w, s);
  }
  red[hh] = s;
  __syncthreads();
  if (part == 0) {
    float v = red[hh] + red[hh + 1] + red[hh + 2] + red[hh + 3] + b_dec[a];
    ws[WS_ATT2 + b * 512 + a] = v;
  }
}

// ---------------- post-loop: scores = H_all @ W_score^T + b_score (128-tile, swizzled LDS) ----------------
__global__ __launch_bounds__(256) void score_kernel(const float* __restrict__ ws, const float* __restrict__ W_score,
                                                    const float* __restrict__ b_score, float* __restrict__ out) {
  __shared__ __align__(16) float As[16 * LSW];
  __shared__ __align__(16) float Bs[16 * LSW];
  const int* iws = (const int*)ws;
  int mt = blockIdx.x, nt = blockIdx.y;
  int R = iws[WS_NB + 49];
  if (mt * 128 >= R) return;
  int tid = threadIdx.x;
  int mvalid = R - mt * 128; if (mvalid > 128) mvalid = 128;
  int nvalid = 10000 - nt * 128; if (nvalid > 128) nvalid = 128;
  float acc[8][8] = {};
  for (int ch = 0; ch < 32; ++ch) {
    __syncthreads();
    stage128_strided(ws + WS_HALL, mt * 128, 512, ch * 16, As, tid, mvalid);
    stage128_strided(W_score, nt * 128, 512, ch * 16, Bs, tid, nvalid);
    __syncthreads();
    gemm_acc128(As, Bs, acc, tid & 15, tid >> 4);
  }
  int tx = tid & 15, ty = tid >> 4;
  int n0 = nt * 128 + ty * 8;
#pragma unroll
  for (int i = 0; i < 8; ++i) {
    int r = mt * 128 + tx * 8 + i;
    if (r >= R) continue;
    int tb = iws[WS_RMAP + r];
    int bb = tb & 63, tt = tb >> 6;
    float* cp = out + (long)bb * 490000 + tt * 10000 + n0;
    if (n0 + 4 <= 10000)
      *(float4*)(cp)     = make_float4(acc[i][0] + b_score[n0],     acc[i][1] + b_score[n0 + 1],
                                       acc[i][2] + b_score[n0 + 2], acc[i][3] + b_score[n0 + 3]);
    if (n0 + 8 <= 10000)
      *(float4*)(cp + 4) = make_float4(acc[i][4] + b_score[n0 + 4], acc[i][5] + b_score[n0 + 5],
                                       acc[i][6] + b_score[n0 + 6], acc[i][7] + b_score[n0 + 7]);
  }
}

// ---------------- launch ----------------
extern "C" void kernel_launch(void* const* d_in, const int* in_sizes, int n_in,
                              void* d_out, int out_size, void* d_ws, size_t ws_size,
                              hipStream_t stream) {
  const float* image   = (const float*)d_in[0];
  const int*   caps    = (const int*)d_in[1];
  const int*   caplens = (const int*)d_in[2];
  const float* emb     = (const float*)d_in[3];
  const float* W_ih    = (const float*)d_in[4];
  const float* W_hh    = (const float*)d_in[5];
  const float* b_ih    = (const float*)d_in[6];
  const float* b_hh    = (const float*)d_in[7];
  const float* W_enc   = (const float*)d_in[8];
  const float* b_enc   = (const float*)d_in[9];
  const float* W_dec   = (const float*)d_in[10];
  const float* b_dec   = (const float*)d_in[11];
  const float* W_full  = (const float*)d_in[12];
  const float* b_full  = (const float*)d_in[13];
  const float* W_score = (const float*)d_in[14];
  const float* b_score = (const float*)d_in[15];
  float* out = (float*)d_out;
  float* ws  = (float*)d_ws;

  setup_kernel<<<1, 64, 0, stream>>>(caps, caplens, ws, out);
  zero_init_kernel<<<2048, 256, 0, stream>>>(out, ws, b_dec);
  encatt_kernel<<<dim3(98, 4), 256, 0, stream>>>(image, W_enc, b_enc, ws);
  for (int t = 0; t < 49; ++t) {
    ectx_kernel<<<dim3(64, 4), 512, 0, stream>>>(ws, image, W_full, b_full, t);
    gates_kernel<<<dim3(16, 16), 256, 0, stream>>>(ws, emb, W_ih, W_hh, t);
    lstm_att2_kernel<<<dim3(64, 4), 512, 0, stream>>>(ws, b_ih, b_hh, W_dec, b_dec, out, t);
  }
  score_kernel<<<dim3(25, 79), 256, 0, stream>>>(ws, W_score, b_score, out);
}

// Round 7
// 2307.478 us; speedup vs baseline: 1.1374x; 1.1374x over previous
//
#include <hip/hip_runtime.h>
#include <math.h>

// ---------------- problem constants ----------------
// B=64, P=196, H=E=A=512, V=10000, T=49, gates=2048, Kx=1536

// ---------------- ws layout (element offsets) ----------------
#define WS_SORT   0             // int[64]
#define WS_DL     64            // int[64]
#define WS_NB     128           // int[64]: nb[0..48], [49]=R
#define WS_ROWOFF 192           // int[64] (50 used)
#define WS_CAPS   256           // int[64*50]
#define WS_RMAP   3456          // int[3136]: t*64+b per compact row
#define WS_H      6592          // float[64*512]
#define WS_C      39360         // float[64*512]
#define WS_ATT2   72128         // float[64*512] (includes b_dec)
#define WS_E      104896        // float[64*200] exp(e) values
#define WS_Z      117696        // float[4][64] expsum partials
#define WS_CTXP   117952        // float[4][64][512] unnormalized ctx partials
#define WS_PG     249024        // float[16][64][2048] gates k-split partials
#define WS_HALL   2346176       // u32[3136*512] compact h rows, packed (bf16hi<<16)|bf16lo
#define WS_ENC    3951808       // float[12544*512] enc_att; after loop: u32[10000*512] packed W_score
// end = 10,374,336 floats = 41.5 MB (proven size)

// ---------------- out layout (floats) ----------------
#define OUT_SCORES 0            // (64,49,10000)
#define OUT_CAPS   31360000     // (64,50)
#define OUT_DL     31363200     // (64,)
#define OUT_W      31363264     // (64,49,196)
#define OUT_SORT   31977920     // (64,)

#define LSW 196                 // swizzled 128-tile row stride (chunks at stride 12)

typedef __attribute__((ext_vector_type(8))) short bf16x8;
typedef __attribute__((ext_vector_type(4))) float f32x4;

__device__ __forceinline__ float sigm(float x) { return 1.f / (1.f + expf(-x)); }

// bf16 round-to-nearest-even of fp32, returned as top-16 bits mask
__device__ __forceinline__ unsigned bf16_hi_bits(float x) {
  unsigned u = __float_as_uint(x);
  return (u + 0x7fffu + ((u >> 16) & 1u)) & 0xffff0000u;
}
// pack x into (bf16 hi << 16) | bf16 lo
__device__ __forceinline__ unsigned pack_bf16x2(float x) {
  unsigned hb = bf16_hi_bits(x);
  float lo = x - __uint_as_float(hb);
  unsigned u = __float_as_uint(lo);
  unsigned lb = ((u + 0x7fffu + ((u >> 16) & 1u)) >> 16) & 0xffffu;
  return hb | lb;
}

// chunk swizzle for 128-tiles: logical col m -> chunk (m>>3) at stride 12
__device__ __forceinline__ int swz128(int m) { return (m >> 3) * 12 + (m & 7); }

// ---------------- 128-tile fp32 helpers (encatt): 256 threads, KC=16, 8x8 micro ----------------
__device__ __forceinline__ void stage128_strided(const float* __restrict__ src, int row0, int ld, int k0,
                                                 float* __restrict__ dst, int tid, int nrows_valid) {
#pragma unroll
  for (int i = 0; i < 2; ++i) {
    int lin = tid + 256 * i;          // 0..511
    int m = lin >> 2, kf = lin & 3;   // m 0..127, kf 0..3
    float4 v = make_float4(0.f, 0.f, 0.f, 0.f);
    if (m < nrows_valid) v = *(const float4*)(src + (long)(row0 + m) * ld + k0 + kf * 4);
    int mc = swz128(m);
    dst[(kf * 4 + 0) * LSW + mc] = v.x;
    dst[(kf * 4 + 1) * LSW + mc] = v.y;
    dst[(kf * 4 + 2) * LSW + mc] = v.z;
    dst[(kf * 4 + 3) * LSW + mc] = v.w;
  }
}

__device__ __forceinline__ void stage128_gather(const float* __restrict__ src, const int* __restrict__ bases,
                                                int k0, float* __restrict__ dst, int tid) {
#pragma unroll
  for (int i = 0; i < 2; ++i) {
    int lin = tid + 256 * i;
    int m = lin >> 2, kf = lin & 3;
    float4 v = *(const float4*)(src + bases[m] + k0 + kf * 4);
    int mc = swz128(m);
    dst[(kf * 4 + 0) * LSW + mc] = v.x;
    dst[(kf * 4 + 1) * LSW + mc] = v.y;
    dst[(kf * 4 + 2) * LSW + mc] = v.z;
    dst[(kf * 4 + 3) * LSW + mc] = v.w;
  }
}

__device__ __forceinline__ void gemm_acc128(const float* __restrict__ As, const float* __restrict__ Bs,
                                            float acc[8][8], int tx, int ty) {
#pragma unroll
  for (int kk = 0; kk < 16; ++kk) {
    const float4* ar = (const float4*)(As + kk * LSW + tx * 12);
    const float4* br = (const float4*)(Bs + kk * LSW + ty * 12);
    float4 a0 = ar[0], a1 = ar[1];
    float4 b0 = br[0], b1 = br[1];
    float av[8] = {a0.x, a0.y, a0.z, a0.w, a1.x, a1.y, a1.z, a1.w};
    float bv[8] = {b0.x, b0.y, b0.z, b0.w, b1.x, b1.y, b1.z, b1.w};
#pragma unroll
    for (int i = 0; i < 8; ++i)
#pragma unroll
      for (int j = 0; j < 8; ++j)
        acc[i][j] = fmaf(av[i], bv[j], acc[i][j]);
  }
}

// ---------------- setup ----------------
__global__ __launch_bounds__(64) void setup_kernel(const int* __restrict__ caps, const int* __restrict__ caplens,
                                                   float* __restrict__ ws, float* __restrict__ out) {
  __shared__ int cl_s[64], so_s[64], dl_s[64], nb_s[49], ro_s[50];
  int i = threadIdx.x;
  cl_s[i] = caplens[i];
  __syncthreads();
  int cli = cl_s[i];
  int r = 0;
  for (int j = 0; j < 64; ++j) {
    int clj = cl_s[j];
    r += (clj > cli) || (clj == cli && j < i);   // stable descending
  }
  so_s[r] = i;
  dl_s[r] = cli - 1;
  __syncthreads();
  int* iws = (int*)ws;
  iws[WS_SORT + i] = so_s[i];
  iws[WS_DL + i] = dl_s[i];
  out[OUT_SORT + i] = (float)so_s[i];
  out[OUT_DL + i] = (float)dl_s[i];
  if (i < 49) {
    int n = 0;
    for (int b = 0; b < 64; ++b) n += (dl_s[b] > i);
    iws[WS_NB + i] = n;
    nb_s[i] = n;
  }
  __syncthreads();
  if (i == 0) {
    int acc = 0;
    for (int t = 0; t < 49; ++t) { ro_s[t] = acc; acc += nb_s[t]; }
    ro_s[49] = acc;
    iws[WS_NB + 49] = acc;
  }
  __syncthreads();
  if (i < 50) iws[WS_ROWOFF + i] = ro_s[i];
  int R = ro_s[49];
  for (int rr = i; rr < 3136; rr += 64) {
    int val = 0;
    if (rr < R) {
      int t = 0;
      while (t < 48 && ro_s[t + 1] <= rr) ++t;
      val = t * 64 + (rr - ro_s[t]);
    }
    iws[WS_RMAP + rr] = val;
  }
  for (int j = i; j < 3200; j += 64) {
    int k = j / 50, jj = j - k * 50;
    int cv = caps[so_s[k] * 50 + jj];
    iws[WS_CAPS + j] = cv;
    out[OUT_CAPS + j] = (float)cv;
  }
}

// ---------------- zero scores+weights+h/c, att2 = b_dec ----------------
__global__ void zero_init_kernel(float* __restrict__ out, float* __restrict__ ws, const float* __restrict__ b_dec) {
  const float4 z = make_float4(0.f, 0.f, 0.f, 0.f);
  float4* out4 = (float4*)out;
  float4* ws4 = (float4*)ws;
  const float4* bd4 = (const float4*)b_dec;
  for (long idx = (long)blockIdx.x * 256 + threadIdx.x; idx < 8018240L; idx += (long)gridDim.x * 256) {
    if (idx < 7840000L) {
      out4[idx] = z;                                   // scores
    } else if (idx < 7993664L) {
      out4[7840816L + (idx - 7840000L)] = z;           // weights
    } else if (idx < 8010048L) {
      ws4[1648L + (idx - 7993664L)] = z;               // h, c
    } else {
      long j = idx - 8010048L;
      ws4[18032L + j] = bd4[j & 127];                  // att2 = b_dec
    }
  }
}

// ---------------- enc_att = feats_sorted @ W_enc^T + b_enc (128-tile, swizzled LDS) ----------------
__global__ __launch_bounds__(256) void encatt_kernel(const float* __restrict__ image, const float* __restrict__ W_enc,
                                                     const float* __restrict__ b_enc, float* __restrict__ ws) {
  __shared__ __align__(16) float As[16 * LSW];
  __shared__ __align__(16) float Bs[16 * LSW];
  __shared__ int rb[128];
  int tid = threadIdx.x;
  const int* iws = (const int*)ws;
  int mt = blockIdx.x, nt = blockIdx.y;
  if (tid < 128) {
    int r = mt * 128 + tid;
    int b = r / 196;
    int p = r - b * 196;
    rb[tid] = iws[WS_SORT + b] * 100352 + p * 512;
  }
  float acc[8][8] = {};
  for (int ch = 0; ch < 32; ++ch) {
    __syncthreads();
    stage128_gather(image, rb, ch * 16, As, tid);
    stage128_strided(W_enc, nt * 128, 512, ch * 16, Bs, tid, 128);
    __syncthreads();
    gemm_acc128(As, Bs, acc, tid & 15, tid >> 4);
  }
  int tx = tid & 15, ty = tid >> 4;
  int r0 = mt * 128 + tx * 8;
  int n0 = nt * 128 + ty * 8;
#pragma unroll
  for (int i = 0; i < 8; ++i) {
    float* cp = ws + WS_ENC + (long)(r0 + i) * 512 + n0;
    *(float4*)(cp)     = make_float4(acc[i][0] + b_enc[n0],     acc[i][1] + b_enc[n0 + 1],
                                     acc[i][2] + b_enc[n0 + 2], acc[i][3] + b_enc[n0 + 3]);
    *(float4*)(cp + 4) = make_float4(acc[i][4] + b_enc[n0 + 4], acc[i][5] + b_enc[n0 + 5],
                                     acc[i][6] + b_enc[n0 + 6], acc[i][7] + b_enc[n0 + 7]);
  }
}

// ---------------- E: round-3 exact — e = relu(enc+att2)@W_full, exp, Z partial, ctx partial ----------------
// grid (64, 4) x 512 threads
__global__ __launch_bounds__(512) void ectx_kernel(float* __restrict__ ws, const float* __restrict__ image,
                                                   const float* __restrict__ W_full, const float* __restrict__ b_full,
                                                   int t) {
  const int* iws = (const int*)ws;
  int b = blockIdx.x;
  if (b >= iws[WS_NB + t]) return;
  int pg = blockIdx.y;
  __shared__ float att2_s[512], wf_s[512], e_s[52];
  int tid = threadIdx.x;
  att2_s[tid] = ws[WS_ATT2 + b * 512 + tid];
  wf_s[tid] = W_full[tid];
  __syncthreads();
  int w = tid >> 6, lane = tid & 63;
  float bf0 = b_full[0];
  for (int idx = w; idx < 49; idx += 8) {
    int p = pg * 49 + idx;
    const float* er = ws + WS_ENC + (long)(b * 196 + p) * 512;
    float acc = 0.f;
#pragma unroll
    for (int a8 = 0; a8 < 8; ++a8) {
      int a = (a8 << 6) + lane;
      float v = er[a] + att2_s[a];
      acc = fmaf(fmaxf(v, 0.f), wf_s[a], acc);
    }
#pragma unroll
    for (int off = 32; off; off >>= 1) acc += __shfl_down(acc, off);
    if (lane == 0) e_s[idx] = expf(acc + bf0);   // |e| small, no max-sub
  }
  __syncthreads();
  if (tid < 49) ws[WS_E + b * 200 + pg * 49 + tid] = e_s[tid];
  if (tid == 0) {
    float zz = 0.f;
    for (int j = 0; j < 49; ++j) zz += e_s[j];
    ws[WS_Z + pg * 64 + b] = zz;
  }
  long sb = (long)iws[WS_SORT + b] * 100352;
  float a0 = 0.f;
  for (int j = 0; j < 49; ++j) {
    a0 = fmaf(e_s[j], image[sb + (long)(pg * 49 + j) * 512 + tid], a0);
  }
  ws[WS_CTXP + pg * 32768 + b * 512 + tid] = a0;
}

// ---------------- G: round-3 exact — gates partial GEMM, 4-wave n-split, K=96/block ----------------
// grid (32, 16) x 256 threads; wave w owns n-cols [w*16, w*16+16)
__global__ __launch_bounds__(256) void gates_kernel(float* __restrict__ ws, const float* __restrict__ emb,
                                                    const float* __restrict__ W_ih, const float* __restrict__ W_hh,
                                                    int t) {
  __shared__ __align__(16) float As[96 * 68];
  __shared__ __align__(16) float Bs[96 * 68];
  __shared__ int rbe[64];
  __shared__ float rcpz_s[64];
  int tid = threadIdx.x;
  int nt = blockIdx.x;   // 0..31
  int ks = blockIdx.y;   // 0..15 (96 k's each)
  int* iws = (int*)ws;
  if (tid < 64) {
    rbe[tid] = iws[WS_CAPS + tid * 50 + t] * 512;
    float zz = ws[WS_Z + tid] + ws[WS_Z + 64 + tid] + ws[WS_Z + 128 + tid] + ws[WS_Z + 192 + tid];
    rcpz_s[tid] = 1.f / zz;
  }
  __syncthreads();
  // stage A and B: 3 sub-chunks of 32 k each
#pragma unroll
  for (int c = 0; c < 3; ++c) {
    int k0 = ks * 96 + c * 32;
#pragma unroll
    for (int i = 0; i < 2; ++i) {
      int lin = tid + 256 * i;        // 0..511
      int kf = lin >> 6;              // 0..7
      int m = lin & 63;               // 0..63
      float4 v;
      if (k0 < 512) {
        v = *(const float4*)(emb + (long)rbe[m] + k0 + kf * 4);
      } else if (k0 < 1024) {
        const float* base = ws + WS_CTXP + m * 512 + (k0 - 512) + kf * 4;
        float4 v0 = *(const float4*)(base);
        float4 v1 = *(const float4*)(base + 32768);
        float4 v2 = *(const float4*)(base + 65536);
        float4 v3 = *(const float4*)(base + 98304);
        float rz = rcpz_s[m];
        v = make_float4((v0.x + v1.x + v2.x + v3.x) * rz, (v0.y + v1.y + v2.y + v3.y) * rz,
                        (v0.z + v1.z + v2.z + v3.z) * rz, (v0.w + v1.w + v2.w + v3.w) * rz);
      } else {
        v = *(const float4*)(ws + WS_H + m * 512 + (k0 - 1024) + kf * 4);
      }
      float* da = As + (c * 32 + kf * 4) * 68 + m;
      da[0] = v.x; da[68] = v.y; da[136] = v.z; da[204] = v.w;
      const float* srcB = (k0 < 1024) ? (W_ih + (long)(nt * 64 + m) * 1024 + k0 + kf * 4)
                                      : (W_hh + (long)(nt * 64 + m) * 512 + (k0 - 1024) + kf * 4);
      float4 bv = *(const float4*)srcB;
      float* db = Bs + (c * 32 + kf * 4) * 68 + m;
      db[0] = bv.x; db[68] = bv.y; db[136] = bv.z; db[204] = bv.w;
    }
  }
  __syncthreads();
  int w = tid >> 6, lane = tid & 63;
  int tx = lane & 7, ty = lane >> 3;
  float acc[8][2] = {};
#pragma unroll 8
  for (int kk = 0; kk < 96; ++kk) {
    const float4* ar = (const float4*)(As + kk * 68 + tx * 8);
    float4 a0 = ar[0], a1 = ar[1];
    float2 bv = *(const float2*)(Bs + kk * 68 + w * 16 + ty * 2);
    float av[8] = {a0.x, a0.y, a0.z, a0.w, a1.x, a1.y, a1.z, a1.w};
#pragma unroll
    for (int i = 0; i < 8; ++i) {
      acc[i][0] = fmaf(av[i], bv.x, acc[i][0]);
      acc[i][1] = fmaf(av[i], bv.y, acc[i][1]);
    }
  }
  float* pg = ws + WS_PG + ks * 131072;
  int j0 = nt * 64 + w * 16 + ty * 2;
#pragma unroll
  for (int i = 0; i < 8; ++i) {
    int b = tx * 8 + i;
    *(float2*)(pg + b * 2048 + j0) = make_float2(acc[i][0], acc[i][1]);
  }
}

// ---------------- S: round-3 exact + packed-bf16 HALL store ----------------
__global__ __launch_bounds__(512) void lstm_att2_kernel(float* __restrict__ ws, const float* __restrict__ b_ih,
                                                        const float* __restrict__ b_hh, const float* __restrict__ W_dec,
                                                        const float* __restrict__ b_dec, float* __restrict__ out, int t) {
  const int* iws = (const int*)ws;
  int b = blockIdx.x;
  int as = blockIdx.y;          // a-split 0..3
  int hh = threadIdx.x;
  int nb = iws[WS_NB + t];
  __shared__ float h_s[512], red[512];
  float gi = b_ih[hh] + b_hh[hh];
  float gf = b_ih[512 + hh] + b_hh[512 + hh];
  float gg = b_ih[1024 + hh] + b_hh[1024 + hh];
  float go = b_ih[1536 + hh] + b_hh[1536 + hh];
  const float* pgp = ws + WS_PG + b * 2048;
#pragma unroll
  for (int ks = 0; ks < 16; ++ks) {
    const float* p = pgp + ks * 131072;
    gi += p[hh]; gf += p[512 + hh]; gg += p[1024 + hh]; go += p[1536 + hh];
  }
  float c = ws[WS_C + b * 512 + hh];
  float cn = sigm(gf) * c + sigm(gi) * tanhf(gg);
  float hn = sigm(go) * tanhf(cn);
  h_s[hh] = hn;
  if (b < nb) {
    if (as == 0) {
      ws[WS_C + b * 512 + hh] = cn;
      ws[WS_H + b * 512 + hh] = hn;
      ((unsigned*)ws)[WS_HALL + (long)(iws[WS_ROWOFF + t] + b) * 512 + hh] = pack_bf16x2(hn);
    }
    if (hh < 49) {   // weights out for this quarter
      float zz = ws[WS_Z + b] + ws[WS_Z + 64 + b] + ws[WS_Z + 128 + b] + ws[WS_Z + 192 + b];
      int p = as * 49 + hh;
      out[OUT_W + (long)(b * 49 + t) * 196 + p] = ws[WS_E + b * 200 + p] / zz;
    }
  }
  __syncthreads();
  // att2(t+1) for a-range [as*128, as*128+128)
  int a = as * 128 + (hh >> 2);
  int part = hh & 3;
  const float* wd = W_dec + (long)a * 512 + part * 128;
  const float* hp = h_s + part * 128;
  float s = 0.f;
#pragma unroll 8
  for (int j = 0; j < 32; ++j) {
    float4 wv = *(const float4*)(wd + 4 * j);
    s = fmaf(hp[4 * j], wv.x, s);
    s = fmaf(hp[4 * j + 1], wv.y, s);
    s = fmaf(hp[4 * j + 2], wv.z, s);
    s = fmaf(hp[4 * j + 3], wv.w, s);
  }
  red[hh] = s;
  __syncthreads();
  if (part == 0) {
    float v = red[hh] + red[hh + 1] + red[hh + 2] + red[hh + 3] + b_dec[a];
    ws[WS_ATT2 + b * 512 + a] = v;
  }
}

// ---------------- pack W_score -> (bf16hi,bf16lo) u32 into WS_ENC (ENC dead after loop) ----------------
__global__ void pack_wscore_kernel(const float* __restrict__ W_score, float* __restrict__ ws) {
  unsigned* dst = (unsigned*)(ws + WS_ENC);
  for (int idx = blockIdx.x * 256 + threadIdx.x; idx < 5120000; idx += gridDim.x * 256) {
    dst[idx] = pack_bf16x2(W_score[idx]);
  }
}

// ---------------- post-loop: scores via bf16-split MFMA ----------------
// D = H(3136x512) @ Wscore^T(512x10000); per block 128m x 128n, 4 waves, wave w: n-range [w*32,+32)
// acc += Ahi*Bhi + Ahi*Blo + Alo*Bhi  (bf16 split-2, err ~2^-18 rel)
__global__ __launch_bounds__(256) void score_kernel(const float* __restrict__ ws,
                                                    const float* __restrict__ b_score, float* __restrict__ out) {
  __shared__ ushort Ah[8192], Al[8192], Bh[8192], Bl[8192];   // [128 rows][64 k] bf16, 16KB each
  const int* iws = (const int*)ws;
  int R = iws[WS_NB + 49];
  int mt = blockIdx.x, nt = blockIdx.y;
  if (mt * 128 >= R) return;
  int tid = threadIdx.x;
  int w = tid >> 6, lane = tid & 63;
  int g = lane >> 4, lm = lane & 15;
  const unsigned* Au = (const unsigned*)(ws + WS_HALL);
  const unsigned* Bu = (const unsigned*)(ws + WS_ENC);
  f32x4 acc[8][2] = {};
  for (int kc = 0; kc < 8; ++kc) {
    int k0 = kc * 64;
    __syncthreads();
    // stage 128x64 u32 for A and B; unpack hi/lo planes with XOR swizzle ^((row&7)<<4)
#pragma unroll
    for (int i = 0; i < 8; ++i) {
      int idx = tid + 256 * i;            // 0..2047
      int row = idx >> 4, c4 = (idx & 15) * 4;
      int off = (row * 128 + c4 * 2) ^ ((row & 7) << 4);
      // A
      uint4 va = make_uint4(0u, 0u, 0u, 0u);
      int ar = mt * 128 + row;
      if (ar < R) va = *(const uint4*)(Au + (long)ar * 512 + k0 + c4);
      *(ushort4*)((char*)Ah + off) = make_ushort4((ushort)(va.x >> 16), (ushort)(va.y >> 16),
                                                  (ushort)(va.z >> 16), (ushort)(va.w >> 16));
      *(ushort4*)((char*)Al + off) = make_ushort4((ushort)(va.x & 0xffff), (ushort)(va.y & 0xffff),
                                                  (ushort)(va.z & 0xffff), (ushort)(va.w & 0xffff));
      // B
      uint4 vb = make_uint4(0u, 0u, 0u, 0u);
      int br = nt * 128 + row;
      if (br < 10000) vb = *(const uint4*)(Bu + (long)br * 512 + k0 + c4);
      *(ushort4*)((char*)Bh + off) = make_ushort4((ushort)(vb.x >> 16), (ushort)(vb.y >> 16),
                                                  (ushort)(vb.z >> 16), (ushort)(vb.w >> 16));
      *(ushort4*)((char*)Bl + off) = make_ushort4((ushort)(vb.x & 0xffff), (ushort)(vb.y & 0xffff),
                                                  (ushort)(vb.z & 0xffff), (ushort)(vb.w & 0xffff));
    }
    __syncthreads();
#pragma unroll
    for (int ks2 = 0; ks2 < 2; ++ks2) {
      int kb = ks2 * 64 + g * 16;        // byte offset of this lane-group's k-slots
      bf16x8 bhf0, bhf1, blf0, blf1;
      {
        int rn0 = w * 32 + lm;
        int off0 = (rn0 * 128 + kb) ^ ((rn0 & 7) << 4);
        bhf0 = *(const bf16x8*)((const char*)Bh + off0);
        blf0 = *(const bf16x8*)((const char*)Bl + off0);
        int rn1 = w * 32 + 16 + lm;
        int off1 = (rn1 * 128 + kb) ^ ((rn1 & 7) << 4);
        bhf1 = *(const bf16x8*)((const char*)Bh + off1);
        blf1 = *(const bf16x8*)((const char*)Bl + off1);
      }
#pragma unroll
      for (int mf = 0; mf < 8; ++mf) {
        int rm = mf * 16 + lm;
        int off = (rm * 128 + kb) ^ ((rm & 7) << 4);
        bf16x8 ah = *(const bf16x8*)((const char*)Ah + off);
        bf16x8 al = *(const bf16x8*)((const char*)Al + off);
        acc[mf][0] = __builtin_amdgcn_mfma_f32_16x16x32_bf16(ah, bhf0, acc[mf][0], 0, 0, 0);
        acc[mf][0] = __builtin_amdgcn_mfma_f32_16x16x32_bf16(ah, blf0, acc[mf][0], 0, 0, 0);
        acc[mf][0] = __builtin_amdgcn_mfma_f32_16x16x32_bf16(al, bhf0, acc[mf][0], 0, 0, 0);
        acc[mf][1] = __builtin_amdgcn_mfma_f32_16x16x32_bf16(ah, bhf1, acc[mf][1], 0, 0, 0);
        acc[mf][1] = __builtin_amdgcn_mfma_f32_16x16x32_bf16(ah, blf1, acc[mf][1], 0, 0, 0);
        acc[mf][1] = __builtin_amdgcn_mfma_f32_16x16x32_bf16(al, bhf1, acc[mf][1], 0, 0, 0);
      }
    }
  }
  // epilogue: D[m = (lane>>4)*4 + r][n = lane&15] per 16x16 frag (m89-verified C/D layout)
#pragma unroll
  for (int mf = 0; mf < 8; ++mf) {
#pragma unroll
    for (int r = 0; r < 4; ++r) {
      int grow = mt * 128 + mf * 16 + g * 4 + r;
      if (grow >= R) continue;
      int tb = iws[WS_RMAP + grow];
      int bb = tb & 63, tt = tb >> 6;
      float* cp = out + (long)bb * 490000 + tt * 10000;
#pragma unroll
      for (int nf = 0; nf < 2; ++nf) {
        int n = nt * 128 + w * 32 + nf * 16 + lm;
        if (n < 10000) cp[n] = acc[mf][nf][r] + b_score[n];
      }
    }
  }
}

// ---------------- launch ----------------
extern "C" void kernel_launch(void* const* d_in, const int* in_sizes, int n_in,
                              void* d_out, int out_size, void* d_ws, size_t ws_size,
                              hipStream_t stream) {
  const float* image   = (const float*)d_in[0];
  const int*   caps    = (const int*)d_in[1];
  const int*   caplens = (const int*)d_in[2];
  const float* emb     = (const float*)d_in[3];
  const float* W_ih    = (const float*)d_in[4];
  const float* W_hh    = (const float*)d_in[5];
  const float* b_ih    = (const float*)d_in[6];
  const float* b_hh    = (const float*)d_in[7];
  const float* W_enc   = (const float*)d_in[8];
  const float* b_enc   = (const float*)d_in[9];
  const float* W_dec   = (const float*)d_in[10];
  const float* b_dec   = (const float*)d_in[11];
  const float* W_full  = (const float*)d_in[12];
  const float* b_full  = (const float*)d_in[13];
  const float* W_score = (const float*)d_in[14];
  const float* b_score = (const float*)d_in[15];
  float* out = (float*)d_out;
  float* ws  = (float*)d_ws;

  setup_kernel<<<1, 64, 0, stream>>>(caps, caplens, ws, out);
  zero_init_kernel<<<2048, 256, 0, stream>>>(out, ws, b_dec);
  encatt_kernel<<<dim3(98, 4), 256, 0, stream>>>(image, W_enc, b_enc, ws);
  for (int t = 0; t < 49; ++t) {
    ectx_kernel<<<dim3(64, 4), 512, 0, stream>>>(ws, image, W_full, b_full, t);
    gates_kernel<<<dim3(32, 16), 256, 0, stream>>>(ws, emb, W_ih, W_hh, t);
    lstm_att2_kernel<<<dim3(64, 4), 512, 0, stream>>>(ws, b_ih, b_hh, W_dec, b_dec, out, t);
  }
  pack_wscore_kernel<<<2048, 256, 0, stream>>>(W_score, ws);
  score_kernel<<<dim3(25, 79), 256, 0, stream>>>(ws, b_score, out);
}